// Round 7
// baseline (12.833 us; speedup 1.0000x reference)
//
#include <hip/hip_runtime.h>

namespace {
constexpr int IC = 32;
constexpr int OC = 32;
constexpr int HW = 1024;            // 32*32 spatial
constexpr int H2 = 16, W2 = 16;     // pooled dims

typedef _Float16 half2v __attribute__((ext_vector_type(2)));

#if defined(__has_builtin)
#if __has_builtin(__builtin_amdgcn_fdot2)
#define HAVE_FDOT2 1
#endif
#endif

__device__ __forceinline__ float dot2acc(half2v a, half2v b, float c) {
#ifdef HAVE_FDOT2
    return __builtin_amdgcn_fdot2(a, b, c, false);   // v_dot2_f32_f16
#else
    return fmaf((float)a.x, (float)b.x, fmaf((float)a.y, (float)b.y, c));
#endif
}

__device__ __forceinline__ half2v u2h(unsigned int u) {
    union { unsigned int u; half2v h; } x; x.u = u; return x.h;
}

__device__ __forceinline__ half2v pk2(float a, float b) {
    union { decltype(__builtin_amdgcn_cvt_pkrtz(0.f, 0.f)) p; half2v h; } x;
    x.p = __builtin_amdgcn_cvt_pkrtz(a, b);   // v_cvt_pkrtz_f16_f32
    return x.h;
}
}

// === R3 structure (best measured: 12.68 us, A/A-reproduced R6) with ONE change:
// the stage phase issues ALL 12 global float4 loads back-to-back before any
// exp/pack/LDS-write. Rationale: the inter-iteration poison fill (262 MB) evicts
// all of L2+L3, so every stage load is a ~900 cy cold HBM miss; the old
// load->use-per-group order exposed ~6 serial miss latencies (~2.3 us). Batching
// leaves one partial-wait and overlaps processing with in-flight misses.
// Everything else verbatim from R3.
__global__ __launch_bounds__(512, 4) void sumprod_fused(
    const float* __restrict__ x, const float* __restrict__ logits,
    float* __restrict__ out)
{
    __shared__ half2v exl[8 * 64 * 16];   // exp(x)   [n8][p64][16 ip slots] 32 KB
    __shared__ half2v ewl[8 * 64 * 16];   // exp(lgt) [o8][p64][16 ip slots] 32 KB
    __shared__ float  wsl[8 * 64];        // softmax denominators [o8][p64]

    const int tid  = threadIdx.x;
    const int lane = tid & 63;
    const int w    = tid >> 6;          // wave id = staging row (n and o)
    const int bid  = blockIdx.x;
    const int s    = bid & 15;          // strip (== h2)
    const int tt   = bid >> 4;          // 0..31
    const int n0   = (tt & 7) * 8;
    const int o0   = (tt >> 3) * 8;

    const int kk    = (tid >> 4) & 3;   // element slot within b128 group
    const int p4    = tid & 15;         // float4 slot in strip
    const int spoff = (2 * s + (p4 >> 3)) * 32 + (p4 & 7) * 4;

    const float* gx = x      + (size_t)(n0 + w) * IC * HW + spoff;
    const float* gw = logits + (size_t)(o0 + w) * IC * HW + spoff;

    // exp + pack f16 pair + swizzled LDS write of one float4-pair task
    auto stage = [&](half2v* buf, const float4& va, const float4& vb, int ip) {
        const float* pa = reinterpret_cast<const float*>(&va);
        const float* pb = reinterpret_cast<const float*>(&vb);
        #pragma unroll
        for (int j = 0; j < 4; ++j) {
            const int p    = (p4 >> 3) * 32 + (p4 & 7) * 4 + j;
            const int slot = (ip >> 2) ^ (((p >> 1) ^ (p >> 3)) & 3);
            buf[(w * 64 + p) * 16 + slot * 4 + (ip & 3)] =
                pk2(__expf(pa[j]), __expf(pb[j]));
        }
    };

    // ---- issue ALL stage loads first: w full (8 float4) + x chunk 0 (4 float4)
    float4 wva[4], wvb[4], xva[2], xvb[2];
    #pragma unroll
    for (int g = 0; g < 4; ++g) {
        const int ip = g * 4 + kk;
        wva[g] = *reinterpret_cast<const float4*>(&gw[(2 * ip) * HW]);
        wvb[g] = *reinterpret_cast<const float4*>(&gw[(2 * ip + 1) * HW]);
    }
    #pragma unroll
    for (int g = 0; g < 2; ++g) {
        const int ip = g * 4 + kk;
        xva[g] = *reinterpret_cast<const float4*>(&gx[(2 * ip) * HW]);
        xvb[g] = *reinterpret_cast<const float4*>(&gx[(2 * ip + 1) * HW]);
    }

    // ---- process in load order: exp + pack + swizzled LDS writes
    #pragma unroll
    for (int g = 0; g < 4; ++g) {
        stage(ewl, wva[g], wvb[g], g * 4 + kk);
    }
    #pragma unroll
    for (int g = 0; g < 2; ++g) {
        stage(exl, xva[g], xvb[g], g * 4 + kk);
    }
    __syncthreads();

    // ---- prefetch x chunk 1 (ip 8..15) into registers; lands under compute-0
    float4 pva[2], pvb[2];
    #pragma unroll
    for (int g = 0; g < 2; ++g) {
        const int ip = (g + 2) * 4 + kk;
        pva[g] = *reinterpret_cast<const float4*>(&gx[(2 * ip) * HW]);
        pvb[g] = *reinterpret_cast<const float4*>(&gx[(2 * ip + 1) * HW]);
    }

    const int swl = ((lane >> 1) ^ (lane >> 3)) & 3;

    // ---- softmax denominators: thread (o=w, p=lane), conflict-free b128 reads
    {
        float ds = 0.f;
        const half2v one2 = {(_Float16)1.f, (_Float16)1.f};
        #pragma unroll
        for (int gg = 0; gg < 4; ++gg) {
            const uint4 B = *reinterpret_cast<const uint4*>(
                &ewl[(w * 64 + lane) * 16 + ((gg ^ swl) * 4)]);
            ds = dot2acc(u2h(B.x), one2, ds);
            ds = dot2acc(u2h(B.y), one2, ds);
            ds = dot2acc(u2h(B.z), one2, ds);
            ds = dot2acc(u2h(B.w), one2, ds);
        }
        wsl[w * 64 + lane] = ds;
    }

    // ---- compute: wave tile 4n x 2o, lane = position
    const int nw = (w & 1) * 4;
    const int ow = (w >> 1) * 2;
    float acc[4][2] = {};

#define D2(AA, BB, K, J) acc[K][J] = dot2acc(u2h(AA), u2h(BB), acc[K][J])
#define QUAD(A_, K_)                                                          \
    D2(A_.x, B0.x, K_, 0); D2(A_.y, B0.y, K_, 0);                             \
    D2(A_.z, B0.z, K_, 0); D2(A_.w, B0.w, K_, 0);                             \
    D2(A_.x, B1.x, K_, 1); D2(A_.y, B1.y, K_, 1);                             \
    D2(A_.z, B1.z, K_, 1); D2(A_.w, B1.w, K_, 1)
#define COMPUTE_GG(GG) {                                                      \
    const int off = ((GG) ^ swl) * 4;                                         \
    const uint4 A0 = *reinterpret_cast<const uint4*>(&exl[((nw + 0) * 64 + lane) * 16 + off]); \
    const uint4 A1 = *reinterpret_cast<const uint4*>(&exl[((nw + 1) * 64 + lane) * 16 + off]); \
    const uint4 A2 = *reinterpret_cast<const uint4*>(&exl[((nw + 2) * 64 + lane) * 16 + off]); \
    const uint4 A3 = *reinterpret_cast<const uint4*>(&exl[((nw + 3) * 64 + lane) * 16 + off]); \
    const uint4 B0 = *reinterpret_cast<const uint4*>(&ewl[((ow + 0) * 64 + lane) * 16 + off]); \
    const uint4 B1 = *reinterpret_cast<const uint4*>(&ewl[((ow + 1) * 64 + lane) * 16 + off]); \
    QUAD(A0, 0); QUAD(A1, 1); QUAD(A2, 2); QUAD(A3, 3); }

    COMPUTE_GG(0);
    COMPUTE_GG(1);

    // ---- write x chunk 1 (slots g=2,3; disjoint from chunk-0 reads -> no barrier
    // needed before, only after). exp applied now; loads landed under compute-0.
    #pragma unroll
    for (int g = 0; g < 2; ++g) {
        const int ip = (g + 2) * 4 + kk;
        stage(exl, pva[g], pvb[g], ip);
    }
    __syncthreads();

    COMPUTE_GG(2);
    COMPUTE_GG(3);

#undef COMPUTE_GG
#undef QUAD
#undef D2

    // ---- epilogue: log, subtract pooled log-denominator, 2x2 pool via shuffles
    const float lw0 = __logf(wsl[(ow + 0) * 64 + lane]);
    const float lw1 = __logf(wsl[(ow + 1) * 64 + lane]);

    #pragma unroll
    for (int k = 0; k < 4; ++k) {
        #pragma unroll
        for (int j = 0; j < 2; ++j) {
            float v = __logf(acc[k][j]) - (j ? lw1 : lw0);
            v += __shfl_xor(v, 1);    // pool over w-pair
            v += __shfl_xor(v, 32);   // pool over h-pair
            if ((lane & 33) == 0) {   // even lane, h_lo == 0
                const int w2 = (lane >> 1) & 15;
                out[((n0 + nw + k) * OC + (o0 + ow + j)) * (H2 * W2) + s * W2 + w2] = v;
            }
        }
    }
}

extern "C" void kernel_launch(void* const* d_in, const int* in_sizes, int n_in,
                              void* d_out, int out_size, void* d_ws, size_t ws_size,
                              hipStream_t stream) {
    const float* x      = (const float*)d_in[0];
    const float* logits = (const float*)d_in[1];
    float* out = (float*)d_out;
    hipLaunchKernelGGL(sumprod_fused, dim3(512), dim3(512), 0, stream,
                       x, logits, out);
}

// Round 8
// 12.675 us; speedup vs baseline: 1.0124x; 1.0124x over previous
//
#include <hip/hip_runtime.h>

namespace {
constexpr int IC = 32;
constexpr int OC = 32;
constexpr int HW = 1024;            // 32*32 spatial
constexpr int H2 = 16, W2 = 16;     // pooled dims

typedef _Float16 half2v __attribute__((ext_vector_type(2)));

#if defined(__has_builtin)
#if __has_builtin(__builtin_amdgcn_fdot2)
#define HAVE_FDOT2 1
#endif
#endif

__device__ __forceinline__ float dot2acc(half2v a, half2v b, float c) {
#ifdef HAVE_FDOT2
    return __builtin_amdgcn_fdot2(a, b, c, false);   // v_dot2_f32_f16
#else
    return fmaf((float)a.x, (float)b.x, fmaf((float)a.y, (float)b.y, c));
#endif
}

__device__ __forceinline__ half2v u2h(unsigned int u) {
    union { unsigned int u; half2v h; } x; x.u = u; return x.h;
}

__device__ __forceinline__ half2v pk2(float a, float b) {
    union { decltype(__builtin_amdgcn_cvt_pkrtz(0.f, 0.f)) p; half2v h; } x;
    x.p = __builtin_amdgcn_cvt_pkrtz(a, b);   // v_cvt_pkrtz_f16_f32
    return x.h;
}
}

// === FINAL: R3 structure (best measured: 12.68 us; A/A-reproduced 12.675 us R6). ===
// Block = 512 threads (8 waves), tile 8n x 8o x one strip (2 h-rows x 32 w = 64 pos).
// Grid 512 = 32 tiles x 16 strips; bid = tt*16 + s -> XCD(bid%8)=s%8 keeps a strip's
// x/logits re-reads on one XCD's L2.
// LDS 66 KB -> 2 blocks/CU. exp values packed f16 pairs; dot via v_dot2_f32_f16.
// Phase skeleton: stage(w full + x chunk0) -> bar -> prefetch x chunk1 ->
// den pass -> compute GG0,GG1 -> restage chunk1 (disjoint slots) -> bar ->
// compute GG2,GG3 -> product-pooled epilogue.
// Session evidence (R4,R5,R7): removing the mid barrier, halving LDS reads/output,
// and batching stage loads ALL fail to beat this -> remaining wall time is a
// launch/dispatch + cold-HBM floor (poison writes 262MB > L3 each iter), not
// kernel pipe work. Structural ceiling reached for this harness regime.
__global__ __launch_bounds__(512, 4) void sumprod_fused(
    const float* __restrict__ x, const float* __restrict__ logits,
    float* __restrict__ out)
{
    __shared__ half2v exl[8 * 64 * 16];   // exp(x)   [n8][p64][16 ip slots] 32 KB
    __shared__ half2v ewl[8 * 64 * 16];   // exp(lgt) [o8][p64][16 ip slots] 32 KB
    __shared__ float  wsl[8 * 64];        // softmax denominators [o8][p64]

    const int tid  = threadIdx.x;
    const int lane = tid & 63;
    const int w    = tid >> 6;          // wave id = staging row (n and o)
    const int bid  = blockIdx.x;
    const int s    = bid & 15;          // strip (== h2)
    const int tt   = bid >> 4;          // 0..31
    const int n0   = (tt & 7) * 8;
    const int o0   = (tt >> 3) * 8;

    const int kk    = (tid >> 4) & 3;   // element slot within b128 group
    const int p4    = tid & 15;         // float4 slot in strip
    const int spoff = (2 * s + (p4 >> 3)) * 32 + (p4 & 7) * 4;

    const float* gx = x      + (size_t)(n0 + w) * IC * HW + spoff;
    const float* gw = logits + (size_t)(o0 + w) * IC * HW + spoff;

    // exp + pack f16 pair + swizzled LDS write of one float4-pair task
    auto stage = [&](half2v* buf, const float4& va, const float4& vb, int ip) {
        const float* pa = reinterpret_cast<const float*>(&va);
        const float* pb = reinterpret_cast<const float*>(&vb);
        #pragma unroll
        for (int j = 0; j < 4; ++j) {
            const int p    = (p4 >> 3) * 32 + (p4 & 7) * 4 + j;
            const int slot = (ip >> 2) ^ (((p >> 1) ^ (p >> 3)) & 3);
            buf[(w * 64 + p) * 16 + slot * 4 + (ip & 3)] =
                pk2(__expf(pa[j]), __expf(pb[j]));
        }
    };

    // ---- stage exp(logits) full (ip 0..15) + exp(x) chunk 0 (ip 0..7)
    #pragma unroll
    for (int g = 0; g < 4; ++g) {
        const int ip = g * 4 + kk;
        const float4 va = *reinterpret_cast<const float4*>(&gw[(2 * ip) * HW]);
        const float4 vb = *reinterpret_cast<const float4*>(&gw[(2 * ip + 1) * HW]);
        stage(ewl, va, vb, ip);
    }
    #pragma unroll
    for (int g = 0; g < 2; ++g) {
        const int ip = g * 4 + kk;
        const float4 va = *reinterpret_cast<const float4*>(&gx[(2 * ip) * HW]);
        const float4 vb = *reinterpret_cast<const float4*>(&gx[(2 * ip + 1) * HW]);
        stage(exl, va, vb, ip);
    }
    __syncthreads();

    // ---- prefetch x chunk 1 (ip 8..15) into registers; lands under compute-0
    float4 pva[2], pvb[2];
    #pragma unroll
    for (int g = 0; g < 2; ++g) {
        const int ip = (g + 2) * 4 + kk;
        pva[g] = *reinterpret_cast<const float4*>(&gx[(2 * ip) * HW]);
        pvb[g] = *reinterpret_cast<const float4*>(&gx[(2 * ip + 1) * HW]);
    }

    const int swl = ((lane >> 1) ^ (lane >> 3)) & 3;

    // ---- softmax denominators: thread (o=w, p=lane), conflict-free b128 reads
    {
        float ds = 0.f;
        const half2v one2 = {(_Float16)1.f, (_Float16)1.f};
        #pragma unroll
        for (int gg = 0; gg < 4; ++gg) {
            const uint4 B = *reinterpret_cast<const uint4*>(
                &ewl[(w * 64 + lane) * 16 + ((gg ^ swl) * 4)]);
            ds = dot2acc(u2h(B.x), one2, ds);
            ds = dot2acc(u2h(B.y), one2, ds);
            ds = dot2acc(u2h(B.z), one2, ds);
            ds = dot2acc(u2h(B.w), one2, ds);
        }
        wsl[w * 64 + lane] = ds;
    }

    // ---- compute: wave tile 4n x 2o, lane = position
    const int nw = (w & 1) * 4;
    const int ow = (w >> 1) * 2;
    float acc[4][2] = {};

#define D2(AA, BB, K, J) acc[K][J] = dot2acc(u2h(AA), u2h(BB), acc[K][J])
#define QUAD(A_, K_)                                                          \
    D2(A_.x, B0.x, K_, 0); D2(A_.y, B0.y, K_, 0);                             \
    D2(A_.z, B0.z, K_, 0); D2(A_.w, B0.w, K_, 0);                             \
    D2(A_.x, B1.x, K_, 1); D2(A_.y, B1.y, K_, 1);                             \
    D2(A_.z, B1.z, K_, 1); D2(A_.w, B1.w, K_, 1)
#define COMPUTE_GG(GG) {                                                      \
    const int off = ((GG) ^ swl) * 4;                                         \
    const uint4 A0 = *reinterpret_cast<const uint4*>(&exl[((nw + 0) * 64 + lane) * 16 + off]); \
    const uint4 A1 = *reinterpret_cast<const uint4*>(&exl[((nw + 1) * 64 + lane) * 16 + off]); \
    const uint4 A2 = *reinterpret_cast<const uint4*>(&exl[((nw + 2) * 64 + lane) * 16 + off]); \
    const uint4 A3 = *reinterpret_cast<const uint4*>(&exl[((nw + 3) * 64 + lane) * 16 + off]); \
    const uint4 B0 = *reinterpret_cast<const uint4*>(&ewl[((ow + 0) * 64 + lane) * 16 + off]); \
    const uint4 B1 = *reinterpret_cast<const uint4*>(&ewl[((ow + 1) * 64 + lane) * 16 + off]); \
    QUAD(A0, 0); QUAD(A1, 1); QUAD(A2, 2); QUAD(A3, 3); }

    COMPUTE_GG(0);
    COMPUTE_GG(1);

    // ---- write x chunk 1 (slots g=2,3; disjoint from chunk-0 reads -> no barrier
    // needed before, only after). exp applied now; loads landed under compute-0.
    #pragma unroll
    for (int g = 0; g < 2; ++g) {
        const int ip = (g + 2) * 4 + kk;
        stage(exl, pva[g], pvb[g], ip);
    }
    __syncthreads();

    COMPUTE_GG(2);
    COMPUTE_GG(3);

#undef COMPUTE_GG
#undef QUAD
#undef D2

    // ---- epilogue: log, subtract pooled log-denominator, 2x2 pool via shuffles
    const float lw0 = __logf(wsl[(ow + 0) * 64 + lane]);
    const float lw1 = __logf(wsl[(ow + 1) * 64 + lane]);

    #pragma unroll
    for (int k = 0; k < 4; ++k) {
        #pragma unroll
        for (int j = 0; j < 2; ++j) {
            float v = __logf(acc[k][j]) - (j ? lw1 : lw0);
            v += __shfl_xor(v, 1);    // pool over w-pair
            v += __shfl_xor(v, 32);   // pool over h-pair
            if ((lane & 33) == 0) {   // even lane, h_lo == 0
                const int w2 = (lane >> 1) & 15;
                out[((n0 + nw + k) * OC + (o0 + ow + j)) * (H2 * W2) + s * W2 + w2] = v;
            }
        }
    }
}

extern "C" void kernel_launch(void* const* d_in, const int* in_sizes, int n_in,
                              void* d_out, int out_size, void* d_ws, size_t ws_size,
                              hipStream_t stream) {
    const float* x      = (const float*)d_in[0];
    const float* logits = (const float*)d_in[1];
    float* out = (float*)d_out;
    hipLaunchKernelGGL(sumprod_fused, dim3(512), dim3(512), 0, stream,
                       x, logits, out);
}